// Round 18
// baseline (163.447 us; speedup 1.0000x reference)
//
#include <hip/hip_runtime.h>
#include <stdint.h>

#define FEAT 128
#define NNODES 512
#define BATCH 4
#define EDGES 97920              // sum_{r=257}^{511} r ; 32 | EDGES
#define BE (BATCH*EDGES)         // 391680
#define NSAMP 5
#define BASE_OFF 32896           // 256*257/2
#define CHUNKS 40                // gumbel blocks per (b,s)
#define GBLOCKS (BATCH*NSAMP*CHUNKS)   // 800
#define NWT (BE/32)              // 12240 wave-tiles (32 edges per wave)
#define MLP_GRID 510             // 510 x 4 waves x 6 tiles = 12240 exactly
#define MAP_BLOCKS 383           // ceil(EDGES/256)
#define PREP_BLOCKS 64           // 64 x 256 = 16384 fragment elements
#define VEC_BLOCK (256 + MAP_BLOCKS + PREP_BLOCKS)        // 703
#define ZERO_BLOCKS 256          // 256 x 1024 float4 = 4 MB adj
#define SETUP_GRID (VEC_BLOCK + 1 + ZERO_BLOCKS)          // 960

typedef float f32x4 __attribute__((ext_vector_type(4)));
typedef short s16x8 __attribute__((ext_vector_type(8)));

// ---------------- threefry2x32 (exact JAX core, key=[0,42]) ------------------
__device__ __forceinline__ void threefry2x32(uint32_t k0, uint32_t k1,
                                             uint32_t& x0, uint32_t& x1) {
  uint32_t k2 = k0 ^ k1 ^ 0x1BD11BDAu;
  x0 += k0; x1 += k1;
#define RR(r) { x0 += x1; x1 = (x1 << (r)) | (x1 >> (32 - (r))); x1 ^= x0; }
  RR(13) RR(15) RR(26) RR(6)   x0 += k1; x1 += k2 + 1u;
  RR(17) RR(29) RR(16) RR(24)  x0 += k2; x1 += k0 + 2u;
  RR(13) RR(15) RR(26) RR(6)   x0 += k0; x1 += k1 + 3u;
  RR(17) RR(29) RR(16) RR(24)  x0 += k1; x1 += k2 + 4u;
  RR(13) RR(15) RR(26) RR(6)   x0 += k2; x1 += k0 + 5u;
#undef RR
}

// partitionable threefry gumbel, fp32 logs (verified passing rounds 7-17)
__device__ __forceinline__ float gumbel_valf(uint32_t n) {
  uint32_t x0 = 0u, x1 = n;
  threefry2x32(0u, 42u, x0, x1);
  uint32_t bits = x0 ^ x1;
  uint32_t fb = (bits >> 9) | 0x3f800000u;
  float f = __uint_as_float(fb) - 1.0f;
  float u = fmaxf(f, 1.1754943508222875e-38f);
  return -logf(-logf(u));
}

// 16-lane (DPP-row) all-lanes sum via row_ror rotate-reduce — VALU pipe.
template <int CTRL>
__device__ __forceinline__ float dpp_ror_add(float v) {
  int t = __builtin_amdgcn_update_dpp(0, __float_as_int(v), CTRL, 0xF, 0xF, true);
  return v + __int_as_float(t);
}
__device__ __forceinline__ float row_sum16(float v) {
  v = dpp_ror_add<0x128>(v);   // row_ror:8
  v = dpp_ror_add<0x124>(v);   // row_ror:4
  v = dpp_ror_add<0x122>(v);   // row_ror:2
  v = dpp_ror_add<0x121>(v);   // row_ror:1
  return v;
}

// ---- fused setup: pq | map | frag-prep (64 blks) | vectors | adj-zero -------
__global__ __launch_bounds__(256) void setup_kernel(
    const float* __restrict__ nodes, const float* __restrict__ W1,
    const float* __restrict__ b1, const float* __restrict__ W2,
    const float* __restrict__ g1, const float* __restrict__ be1,
    const float* __restrict__ b2, const float* __restrict__ g2,
    const float* __restrict__ be2, const float* __restrict__ W3,
    const float* __restrict__ b3, float* __restrict__ P, float* __restrict__ Q,
    int2* __restrict__ map, unsigned short* __restrict__ GFH,
    unsigned short* __restrict__ GFL, float* __restrict__ SG,
    float* __restrict__ SB, float* __restrict__ GW3, float* __restrict__ SC,
    unsigned long long* __restrict__ slots, float* __restrict__ adj) {
  const int blk = blockIdx.x;
  const int tid = threadIdx.x;
  if (blk < 256) {
    // ---- pq: P = nodes @ W1_top + b1, Q = nodes @ W1_bot (verified) ----
    __shared__ float snode[8][FEAT];
    const int row0 = blk * 8;
    for (int i = tid; i < 8 * FEAT; i += 256)
      snode[i >> 7][i & 127] = nodes[row0 * FEAT + i];
    __syncthreads();
    const int j = tid & 127;
    const int half = tid >> 7;
    const float* w = W1 + half * FEAT * FEAT + j;
    float acc[8] = {0, 0, 0, 0, 0, 0, 0, 0};
    for (int k4 = 0; k4 < 32; ++k4) {
      const float* wp = w + (k4 * 4) * FEAT;
      const float w0 = wp[0], w1 = wp[FEAT], w2 = wp[2 * FEAT], w3 = wp[3 * FEAT];
#pragma unroll
      for (int m = 0; m < 8; ++m) {
        const float4 nv = *(const float4*)&snode[m][k4 * 4];
        acc[m] = fmaf(nv.x, w0, acc[m]);
        acc[m] = fmaf(nv.y, w1, acc[m]);
        acc[m] = fmaf(nv.z, w2, acc[m]);
        acc[m] = fmaf(nv.w, w3, acc[m]);
      }
    }
    const float bv = half ? 0.0f : b1[j];
    float* out = half ? Q : P;
#pragma unroll
    for (int m = 0; m < 8; ++m) out[(row0 + m) * FEAT + j] = acc[m] + bv;
  } else if (blk < 256 + MAP_BLOCKS) {
    // ---- map: edge -> (sink, src) ----
    int e = (blk - 256) * 256 + tid;
    if (e < EDGES) {
      double x = (double)(e + BASE_OFF);
      int s = (int)((1.0 + sqrt(1.0 + 8.0 * x)) * 0.5);
      while ((long long)s * (s - 1) / 2 - BASE_OFF > e) --s;
      while ((long long)(s + 1) * s / 2 - BASE_OFF <= e) ++s;
      int src = e - (int)((long long)s * (s - 1) / 2 - BASE_OFF);
      map[e] = make_int2(s, src);
    }
  } else if (blk < VEC_BLOCK) {
    // ---- frag prep: one element per thread (layout verified rounds 8-17) ----
    const int idx = (blk - (256 + MAP_BLOCKS)) * 256 + tid;   // < 16384
    const int j = idx & 7;
    const int lane = (idx >> 3) & 63;
    const int nt = (idx >> 9) & 7;
    const int kt = (idx >> 12) & 3;
    const int n = nt * 16 + (lane & 15);
    const int k = kt * 32 + ((lane >> 4) << 3) + j;
    const float g = g1[k] * W2[k * FEAT + n];
    const uint32_t gu = __float_as_uint(g);
    const float d = g - __uint_as_float(gu & 0xFFFF0000u);
    GFH[idx] = (unsigned short)(gu >> 16);
    GFL[idx] = (unsigned short)(__float_as_uint(d) >> 16);
  } else if (blk == VEC_BLOCK) {
    // ---- vectors: SG/SB (2-way k-split), GW3, SC; zero gumbel slots ----
    __shared__ float partS[256], partB[256], rg[128], rb[128];
    if (tid < BATCH * NSAMP + 1) slots[tid] = 0ull;   // 20 slots + counter
    {
      const int n = tid & 127, kh = tid >> 7;
      float sg = 0.f, sb = 0.f;
      const int k0 = kh * 64;
#pragma unroll 8
      for (int k = k0; k < k0 + 64; ++k) {
        const float w = W2[k * FEAT + n];
        sg = fmaf(g1[k], w, sg);
        sb = fmaf(be1[k], w, sb);
      }
      partS[tid] = sg;
      partB[tid] = sb;
    }
    __syncthreads();
    if (tid < 128) {
      SG[tid] = partS[tid] + partS[tid + 128];
      SB[tid] = partB[tid] + partB[tid + 128] + b2[tid];
      const float gw = g2[tid] * W3[tid];
      GW3[tid] = gw;
      rg[tid] = gw;
      rb[tid] = be2[tid] * W3[tid];
    }
    __syncthreads();
    for (int off = 64; off; off >>= 1) {
      if (tid < off) { rg[tid] += rg[tid + off]; rb[tid] += rb[tid + off]; }
      __syncthreads();
    }
    if (tid == 0) { SC[0] = rg[0]; SC[1] = rb[0] + b3[0]; }
  } else {
    // ---- zero adj (replaces hipMemsetAsync dispatch) ----
    float4* a4 = (float4*)adj;
    const int base = (blk - (VEC_BLOCK + 1)) * 1024 + tid;
#pragma unroll
    for (int jj = 0; jj < 4; ++jj)
      a4[base + jj * 256] = make_float4(0.f, 0.f, 0.f, 0.f);
  }
}

// ---------------- main MLP kernel (R17 minus in-loop sched fences) ------------
// Change vs R17: the per-group sched_barrier(0) in the MFMA loop is removed
// (live set is now ~120 arch regs — the R11-era anti-spill fences were
// blocking cross-group DS/MFMA overlap). Stage-1 fence kept.
// Tripwire: WRITE_SIZE must stay ~1530 KB; growth = hoist-spill returned.
__global__ __launch_bounds__(256, 2) void mlp_kernel(
    const float* __restrict__ P, const float* __restrict__ Q,
    const int2* __restrict__ map,
    const unsigned short* __restrict__ GFH,
    const unsigned short* __restrict__ GFL,
    const float* __restrict__ SG, const float* __restrict__ SB,
    const float* __restrict__ GW3, const float* __restrict__ SC,
    float* __restrict__ logits) {
  __shared__ s16x8 sBH[2048];                // 32 KB
  __shared__ s16x8 sBL[2048];                // 32 KB
  const int tid = threadIdx.x;
  const int lane = tid & 63;
  const int wave = tid >> 6;
  const int cl = lane & 15;                   // C/D col lane; A m-row lane
  const int qd = lane >> 4;                   // quad: A k-group, C/D row group

  {
    const float4* s1p = (const float4*)GFH;
    const float4* s2p = (const float4*)GFL;
    float4* d1 = (float4*)sBH;
    float4* d2 = (float4*)sBL;
    for (int i = tid; i < 2048; i += 256) { d1[i] = s1p[i]; d2[i] = s2p[i]; }
  }
  __syncthreads();

  const float sgw3 = SC[0], cb = SC[1];

#pragma unroll 1
  for (int it = 0; it < 6; ++it) {           // uniform trip count
    const int wt = blockIdx.x * 24 + it * 4 + wave;   // < 12240 always
    const int g0 = wt * 32;
    const int b = g0 / EDGES;                // 32 | EDGES: no batch crossing
    const int e0 = g0 - b * EDGES;
    const int bofs = (b << 9);

    // ---- stage 1: raw h -> bf16 hi/lo A-frags at load; stats as partials ----
    s16x8 Ah[2][4], Al[2][4];
    float s1v[2], q1v[2];
#pragma unroll
    for (int mt = 0; mt < 2; ++mt) {
      const int2 ss = map[e0 + mt * 16 + cl];
      const float* pr = P + ((size_t)(bofs + ss.x) << 7) + qd * 8;
      const float* qr = Q + ((size_t)(bofs + ss.y) << 7) + qd * 8;
      float s1 = 0.f, q1 = 0.f;
#pragma unroll
      for (int kt = 0; kt < 4; ++kt) {
        const float4 pa = *(const float4*)(pr + kt * 32);
        const float4 pb = *(const float4*)(pr + kt * 32 + 4);
        const float4 qa = *(const float4*)(qr + kt * 32);
        const float4 qb = *(const float4*)(qr + kt * 32 + 4);
        const float uu[8] = {
            fmaxf(pa.x + qa.x, 0.f), fmaxf(pa.y + qa.y, 0.f),
            fmaxf(pa.z + qa.z, 0.f), fmaxf(pa.w + qa.w, 0.f),
            fmaxf(pb.x + qb.x, 0.f), fmaxf(pb.y + qb.y, 0.f),
            fmaxf(pb.z + qb.z, 0.f), fmaxf(pb.w + qb.w, 0.f)};
#pragma unroll
        for (int j = 0; j < 8; ++j) {
          const float h = uu[j];
          s1 += h;
          q1 = fmaf(h, h, q1);
          const uint32_t xu = __float_as_uint(h);
          const float d = h - __uint_as_float(xu & 0xFFFF0000u);
          Ah[mt][kt][j] = (short)(xu >> 16);
          Al[mt][kt][j] = (short)(__float_as_uint(d) >> 16);
        }
      }
      s1v[mt] = s1;
      q1v[mt] = q1;
    }
    __builtin_amdgcn_sched_barrier(0);       // single stage-1 fence (R17)

    // ---- stage 2: 3-product bf16-split MFMA; 2-slot depth-2 B pipeline ----
    f32x4 acc[2][8];
#pragma unroll
    for (int mt = 0; mt < 2; ++mt)
#pragma unroll
      for (int nt = 0; nt < 8; ++nt) acc[mt][nt] = (f32x4){0.f, 0.f, 0.f, 0.f};

    s16x8 Bh[2][2], Bl[2][2];                // [slot][pair] — 32 VGPRs
#pragma unroll
    for (int s = 0; s < 2; ++s) {            // preload groups 0,1
      const int base = ((s >> 2) * 8 + (s & 3) * 2) * 64 + lane;
      Bh[s][0] = sBH[base];      Bl[s][0] = sBL[base];
      Bh[s][1] = sBH[base + 64]; Bl[s][1] = sBL[base + 64];
    }
#pragma unroll
    for (int g = 0; g < 16; ++g) {           // g = kt*4 + np
      const int kt = g >> 2;
      const int n0 = (g & 3) * 2, n1 = n0 + 1;
      const int sl = g & 1;
      acc[0][n0] = __builtin_amdgcn_mfma_f32_16x16x32_bf16(Ah[0][kt], Bh[sl][0], acc[0][n0], 0, 0, 0);
      acc[1][n0] = __builtin_amdgcn_mfma_f32_16x16x32_bf16(Ah[1][kt], Bh[sl][0], acc[1][n0], 0, 0, 0);
      acc[0][n1] = __builtin_amdgcn_mfma_f32_16x16x32_bf16(Ah[0][kt], Bh[sl][1], acc[0][n1], 0, 0, 0);
      acc[1][n1] = __builtin_amdgcn_mfma_f32_16x16x32_bf16(Ah[1][kt], Bh[sl][1], acc[1][n1], 0, 0, 0);
      acc[0][n0] = __builtin_amdgcn_mfma_f32_16x16x32_bf16(Al[0][kt], Bh[sl][0], acc[0][n0], 0, 0, 0);
      acc[1][n0] = __builtin_amdgcn_mfma_f32_16x16x32_bf16(Al[1][kt], Bh[sl][0], acc[1][n0], 0, 0, 0);
      acc[0][n1] = __builtin_amdgcn_mfma_f32_16x16x32_bf16(Al[0][kt], Bh[sl][1], acc[0][n1], 0, 0, 0);
      acc[1][n1] = __builtin_amdgcn_mfma_f32_16x16x32_bf16(Al[1][kt], Bh[sl][1], acc[1][n1], 0, 0, 0);
      acc[0][n0] = __builtin_amdgcn_mfma_f32_16x16x32_bf16(Ah[0][kt], Bl[sl][0], acc[0][n0], 0, 0, 0);
      acc[1][n0] = __builtin_amdgcn_mfma_f32_16x16x32_bf16(Ah[1][kt], Bl[sl][0], acc[1][n0], 0, 0, 0);
      acc[0][n1] = __builtin_amdgcn_mfma_f32_16x16x32_bf16(Ah[0][kt], Bl[sl][1], acc[0][n1], 0, 0, 0);
      acc[1][n1] = __builtin_amdgcn_mfma_f32_16x16x32_bf16(Ah[1][kt], Bl[sl][1], acc[1][n1], 0, 0, 0);
      if (g < 14) {                          // refill this slot for group g+2
        const int g2 = g + 2;
        const int base = ((g2 >> 2) * 8 + (g2 & 3) * 2) * 64 + lane;
        Bh[sl][0] = sBH[base];      Bl[sl][0] = sBL[base];
        Bh[sl][1] = sBH[base + 64]; Bl[sl][1] = sBL[base + 64];
      }
      // (per-group sched_barrier removed — R18)
    }

    // ---- finalize LN1 stats (post-MFMA) ----
    float mu[2], rs[2];
#pragma unroll
    for (int mt = 0; mt < 2; ++mt) {
      float s1 = s1v[mt], q1 = q1v[mt];
      s1 += __shfl_xor(s1, 16, 64);
      s1 += __shfl_xor(s1, 32, 64);
      q1 += __shfl_xor(q1, 16, 64);
      q1 += __shfl_xor(q1, 32, 64);
      mu[mt] = s1 * (1.0f / 128.0f);
      const float var = fmaxf(q1 * (1.0f / 128.0f) - mu[mt] * mu[mt], 0.0f);
      rs[mt] = rsqrtf(var + 1e-5f);
    }

    // ---- epilogue: LN1 fold, relu, LN2+W3 fold; DPP row reductions ----
    int zz;
    asm volatile("v_mov_b32 %0, 0" : "=v"(zz));
    float SGn[8], SBn[8], GWn[8];
#pragma unroll
    for (int nt = 0; nt < 8; ++nt) {
      const int n = nt * 16 + cl + zz;
      SGn[nt] = SG[n];
      SBn[nt] = SB[n];
      GWn[nt] = GW3[n];
    }
#pragma unroll
    for (int mt = 0; mt < 2; ++mt) {
#pragma unroll
      for (int r = 0; r < 4; ++r) {
        const int me = qd * 4 + r;            // edge row within mt-tile
        const float mue = __shfl(mu[mt], me, 64);
        const float rse = __shfl(rs[mt], me, 64);
        float s2 = 0.f, q2 = 0.f, t = 0.f;
#pragma unroll
        for (int nt = 0; nt < 8; ++nt) {
          const float Sraw = acc[mt][nt][r];
          const float z = fmaf(rse, fmaf(-mue, SGn[nt], Sraw), SBn[nt]);
          const float h2 = fmaxf(z, 0.f);
          s2 += h2;
          q2 = fmaf(h2, h2, q2);
          t = fmaf(h2, GWn[nt], t);
        }
        s2 = row_sum16(s2);                   // DPP (VALU), not DS
        q2 = row_sum16(q2);
        t  = row_sum16(t);
        if (cl == 0) {
          const float mu2 = s2 * (1.0f / 128.0f);
          const float var2 = fmaxf(q2 * (1.0f / 128.0f) - mu2 * mu2, 0.0f);
          const float rs2 = rsqrtf(var2 + 1e-5f);
          logits[g0 + mt * 16 + me] = rs2 * (t - mu2 * sgw3) + cb;
        }
      }
    }
  }
}

// ------- gumbel argmax + fused decode: per-block best -> atomicMax slots; ----
// the last-finishing block scatters the 20 winners into adj (one dispatch).
__global__ __launch_bounds__(256) void gumbel_kernel(
    const float* __restrict__ logits, unsigned long long* __restrict__ slots,
    const int2* __restrict__ map, float* __restrict__ adj) {
  const int bs = blockIdx.x / CHUNKS;     // b*5 + s
  const int chunk = blockIdx.x % CHUNKS;
  const int b = bs / NSAMP;
  const float* lg = logits + b * EDGES;
  float best = -1e30f; int bi = 0x7fffffff;
  for (int e = chunk * 256 + threadIdx.x; e < EDGES; e += CHUNKS * 256) {
    uint32_t n = (uint32_t)(bs * EDGES + e);
    float val = lg[e] + gumbel_valf(n);
    if (val > best) { best = val; bi = e; }
  }
  __shared__ float sv[256];
  __shared__ int si[256];
  __shared__ int slast;
  sv[threadIdx.x] = best; si[threadIdx.x] = bi;
  __syncthreads();
  for (int off = 128; off; off >>= 1) {
    if (threadIdx.x < off) {
      float ov = sv[threadIdx.x + off]; int oi = si[threadIdx.x + off];
      if (ov > sv[threadIdx.x] ||
          (ov == sv[threadIdx.x] && oi < si[threadIdx.x])) {
        sv[threadIdx.x] = ov; si[threadIdx.x] = oi;
      }
    }
    __syncthreads();
  }
  if (threadIdx.x == 0) {
    // pack: sortable-float key (desc value), ~idx low bits (asc idx tie-break)
    uint32_t u = __float_as_uint(sv[0]);
    u = (u & 0x80000000u) ? ~u : (u | 0x80000000u);
    const unsigned long long pk =
        ((unsigned long long)u << 32) | (uint32_t)(~(uint32_t)si[0]);
    atomicMax(&slots[bs], pk);
    __threadfence();
    const unsigned long long done = atomicAdd(&slots[BATCH * NSAMP], 1ull);
    slast = (done == (unsigned long long)(GBLOCKS - 1)) ? 1 : 0;
  }
  __syncthreads();
  if (slast) {
    __threadfence();
    const int l = threadIdx.x;
    if (l < BATCH * NSAMP) {
      const unsigned long long pk = atomicMax(&slots[l], 0ull);  // coherent read
      const int e = (int)(~(uint32_t)(pk & 0xFFFFFFFFu));
      const int bb = l / NSAMP;
      const int2 ss = map[e];
      adj[((bb * NNODES) + ss.x) * NNODES + ss.y] = 1.0f;
    }
  }
}

extern "C" void kernel_launch(void* const* d_in, const int* in_sizes, int n_in,
                              void* d_out, int out_size, void* d_ws, size_t ws_size,
                              hipStream_t stream) {
  const float* nodes = (const float*)d_in[0];
  const float* W1  = (const float*)d_in[1];
  const float* b1  = (const float*)d_in[2];
  const float* g1  = (const float*)d_in[3];
  const float* be1 = (const float*)d_in[4];
  const float* W2  = (const float*)d_in[5];
  const float* b2  = (const float*)d_in[6];
  const float* g2  = (const float*)d_in[7];
  const float* be2 = (const float*)d_in[8];
  const float* W3  = (const float*)d_in[9];
  const float* b3  = (const float*)d_in[10];
  float* adj = (float*)d_out;

  char* ws = (char*)d_ws;
  float* P       = (float*)(ws);                       // 1 MB  [2048][128]
  float* Q       = (float*)(ws + (1 << 20));           // 1 MB
  int2*  map     = (int2*) (ws + (2 << 20));           // 783 KB
  float* logits  = (float*)(ws + (3 << 20));           // 1.57 MB
  unsigned short* GFH = (unsigned short*)(ws + (5 << 20));           // 32 KB
  unsigned short* GFL = (unsigned short*)(ws + (5 << 20) + 32768);   // 32 KB
  float* SG      = (float*)(ws + (5 << 20) + 65536);
  float* SB      = (float*)(ws + (5 << 20) + 66048);
  float* GW3     = (float*)(ws + (5 << 20) + 66560);
  float* SC      = (float*)(ws + (5 << 20) + 67072);
  unsigned long long* slots = (unsigned long long*)(ws + (5 << 20) + 131072);

  setup_kernel<<<SETUP_GRID, 256, 0, stream>>>(
      nodes, W1, b1, W2, g1, be1, b2, g2, be2, W3, b3,
      P, Q, map, GFH, GFL, SG, SB, GW3, SC, slots, adj);
  mlp_kernel<<<MLP_GRID, 256, 0, stream>>>(P, Q, map, GFH, GFL,
                                           SG, SB, GW3, SC, logits);
  gumbel_kernel<<<GBLOCKS, 256, 0, stream>>>(logits, slots, map, adj);
}

// Round 19
// 151.929 us; speedup vs baseline: 1.0758x; 1.0758x over previous
//
#include <hip/hip_runtime.h>
#include <stdint.h>

#define FEAT 128
#define NNODES 512
#define BATCH 4
#define EDGES 97920              // sum_{r=257}^{511} r ; 32 | EDGES
#define BE (BATCH*EDGES)         // 391680
#define NSAMP 5
#define BASE_OFF 32896           // 256*257/2
#define CHUNKS 40                // gumbel blocks per (b,s)
#define NWT (BE/32)              // 12240 wave-tiles (32 edges per wave)
#define MLP_GRID 510             // 510 x 4 waves x 6 tiles = 12240 exactly
#define MAP_BLOCKS 383           // ceil(EDGES/256)
#define PREP_BLOCKS 64           // 64 x 256 = 16384 fragment elements
#define VEC_BLOCK (256 + MAP_BLOCKS + PREP_BLOCKS)        // 703
#define ZERO_BLOCKS 256          // 256 x 1024 float4 = 4 MB adj
#define SETUP_GRID (VEC_BLOCK + 1 + ZERO_BLOCKS)          // 960

typedef float f32x4 __attribute__((ext_vector_type(4)));
typedef short s16x8 __attribute__((ext_vector_type(8)));

// ---------------- threefry2x32 (exact JAX core, key=[0,42]) ------------------
__device__ __forceinline__ void threefry2x32(uint32_t k0, uint32_t k1,
                                             uint32_t& x0, uint32_t& x1) {
  uint32_t k2 = k0 ^ k1 ^ 0x1BD11BDAu;
  x0 += k0; x1 += k1;
#define RR(r) { x0 += x1; x1 = (x1 << (r)) | (x1 >> (32 - (r))); x1 ^= x0; }
  RR(13) RR(15) RR(26) RR(6)   x0 += k1; x1 += k2 + 1u;
  RR(17) RR(29) RR(16) RR(24)  x0 += k2; x1 += k0 + 2u;
  RR(13) RR(15) RR(26) RR(6)   x0 += k0; x1 += k1 + 3u;
  RR(17) RR(29) RR(16) RR(24)  x0 += k1; x1 += k2 + 4u;
  RR(13) RR(15) RR(26) RR(6)   x0 += k2; x1 += k0 + 5u;
#undef RR
}

// partitionable threefry gumbel, fp32 logs (verified passing rounds 7-18)
__device__ __forceinline__ float gumbel_valf(uint32_t n) {
  uint32_t x0 = 0u, x1 = n;
  threefry2x32(0u, 42u, x0, x1);
  uint32_t bits = x0 ^ x1;
  uint32_t fb = (bits >> 9) | 0x3f800000u;
  float f = __uint_as_float(fb) - 1.0f;
  float u = fmaxf(f, 1.1754943508222875e-38f);
  return -logf(-logf(u));
}

// 16-lane (DPP-row) all-lanes sum via row_ror rotate-reduce — VALU pipe.
template <int CTRL>
__device__ __forceinline__ float dpp_ror_add(float v) {
  int t = __builtin_amdgcn_update_dpp(0, __float_as_int(v), CTRL, 0xF, 0xF, true);
  return v + __int_as_float(t);
}
__device__ __forceinline__ float row_sum16(float v) {
  v = dpp_ror_add<0x128>(v);   // row_ror:8
  v = dpp_ror_add<0x124>(v);   // row_ror:4
  v = dpp_ror_add<0x122>(v);   // row_ror:2
  v = dpp_ror_add<0x121>(v);   // row_ror:1
  return v;
}

// ---- fused setup: pq | map | frag-prep (64 blks) | vectors | adj-zero -------
__global__ __launch_bounds__(256) void setup_kernel(
    const float* __restrict__ nodes, const float* __restrict__ W1,
    const float* __restrict__ b1, const float* __restrict__ W2,
    const float* __restrict__ g1, const float* __restrict__ be1,
    const float* __restrict__ b2, const float* __restrict__ g2,
    const float* __restrict__ be2, const float* __restrict__ W3,
    const float* __restrict__ b3, float* __restrict__ P, float* __restrict__ Q,
    int2* __restrict__ map, unsigned short* __restrict__ GFH,
    unsigned short* __restrict__ GFL, float* __restrict__ SG,
    float* __restrict__ SB, float* __restrict__ GW3, float* __restrict__ SC,
    float* __restrict__ adj) {
  const int blk = blockIdx.x;
  const int tid = threadIdx.x;
  if (blk < 256) {
    // ---- pq: P = nodes @ W1_top + b1, Q = nodes @ W1_bot (verified) ----
    __shared__ float snode[8][FEAT];
    const int row0 = blk * 8;
    for (int i = tid; i < 8 * FEAT; i += 256)
      snode[i >> 7][i & 127] = nodes[row0 * FEAT + i];
    __syncthreads();
    const int j = tid & 127;
    const int half = tid >> 7;
    const float* w = W1 + half * FEAT * FEAT + j;
    float acc[8] = {0, 0, 0, 0, 0, 0, 0, 0};
    for (int k4 = 0; k4 < 32; ++k4) {
      const float* wp = w + (k4 * 4) * FEAT;
      const float w0 = wp[0], w1 = wp[FEAT], w2 = wp[2 * FEAT], w3 = wp[3 * FEAT];
#pragma unroll
      for (int m = 0; m < 8; ++m) {
        const float4 nv = *(const float4*)&snode[m][k4 * 4];
        acc[m] = fmaf(nv.x, w0, acc[m]);
        acc[m] = fmaf(nv.y, w1, acc[m]);
        acc[m] = fmaf(nv.z, w2, acc[m]);
        acc[m] = fmaf(nv.w, w3, acc[m]);
      }
    }
    const float bv = half ? 0.0f : b1[j];
    float* out = half ? Q : P;
#pragma unroll
    for (int m = 0; m < 8; ++m) out[(row0 + m) * FEAT + j] = acc[m] + bv;
  } else if (blk < 256 + MAP_BLOCKS) {
    // ---- map: edge -> (sink, src) ----
    int e = (blk - 256) * 256 + tid;
    if (e < EDGES) {
      double x = (double)(e + BASE_OFF);
      int s = (int)((1.0 + sqrt(1.0 + 8.0 * x)) * 0.5);
      while ((long long)s * (s - 1) / 2 - BASE_OFF > e) --s;
      while ((long long)(s + 1) * s / 2 - BASE_OFF <= e) ++s;
      int src = e - (int)((long long)s * (s - 1) / 2 - BASE_OFF);
      map[e] = make_int2(s, src);
    }
  } else if (blk < VEC_BLOCK) {
    // ---- frag prep: one element per thread (layout verified rounds 8-18) ----
    const int idx = (blk - (256 + MAP_BLOCKS)) * 256 + tid;   // < 16384
    const int j = idx & 7;
    const int lane = (idx >> 3) & 63;
    const int nt = (idx >> 9) & 7;
    const int kt = (idx >> 12) & 3;
    const int n = nt * 16 + (lane & 15);
    const int k = kt * 32 + ((lane >> 4) << 3) + j;
    const float g = g1[k] * W2[k * FEAT + n];
    const uint32_t gu = __float_as_uint(g);
    const float d = g - __uint_as_float(gu & 0xFFFF0000u);
    GFH[idx] = (unsigned short)(gu >> 16);
    GFL[idx] = (unsigned short)(__float_as_uint(d) >> 16);
  } else if (blk == VEC_BLOCK) {
    // ---- vectors: SG/SB (2-way k-split), GW3, SC (tree reduce) ----
    __shared__ float partS[256], partB[256], rg[128], rb[128];
    {
      const int n = tid & 127, kh = tid >> 7;
      float sg = 0.f, sb = 0.f;
      const int k0 = kh * 64;
#pragma unroll 8
      for (int k = k0; k < k0 + 64; ++k) {
        const float w = W2[k * FEAT + n];
        sg = fmaf(g1[k], w, sg);
        sb = fmaf(be1[k], w, sb);
      }
      partS[tid] = sg;
      partB[tid] = sb;
    }
    __syncthreads();
    if (tid < 128) {
      SG[tid] = partS[tid] + partS[tid + 128];
      SB[tid] = partB[tid] + partB[tid + 128] + b2[tid];
      const float gw = g2[tid] * W3[tid];
      GW3[tid] = gw;
      rg[tid] = gw;
      rb[tid] = be2[tid] * W3[tid];
    }
    __syncthreads();
    for (int off = 64; off; off >>= 1) {
      if (tid < off) { rg[tid] += rg[tid + off]; rb[tid] += rb[tid + off]; }
      __syncthreads();
    }
    if (tid == 0) { SC[0] = rg[0]; SC[1] = rb[0] + b3[0]; }
  } else {
    // ---- zero adj (replaces hipMemsetAsync dispatch) ----
    float4* a4 = (float4*)adj;
    const int base = (blk - (VEC_BLOCK + 1)) * 1024 + tid;
#pragma unroll
    for (int jj = 0; jj < 4; ++jj)
      a4[base + jj * 256] = make_float4(0.f, 0.f, 0.f, 0.f);
  }
}

// ---------------- main MLP kernel (R16 best config, verified) -----------------
// Per-mt stage-1 fences + per-group MFMA fences (anti-spill, empirically
// optimal across R13-R18), DPP epilogue reductions, 2-slot depth-2 B pipeline.
__global__ __launch_bounds__(256, 2) void mlp_kernel(
    const float* __restrict__ P, const float* __restrict__ Q,
    const int2* __restrict__ map,
    const unsigned short* __restrict__ GFH,
    const unsigned short* __restrict__ GFL,
    const float* __restrict__ SG, const float* __restrict__ SB,
    const float* __restrict__ GW3, const float* __restrict__ SC,
    float* __restrict__ logits) {
  __shared__ s16x8 sBH[2048];                // 32 KB
  __shared__ s16x8 sBL[2048];                // 32 KB
  const int tid = threadIdx.x;
  const int lane = tid & 63;
  const int wave = tid >> 6;
  const int cl = lane & 15;                   // C/D col lane; A m-row lane
  const int qd = lane >> 4;                   // quad: A k-group, C/D row group

  {
    const float4* s1p = (const float4*)GFH;
    const float4* s2p = (const float4*)GFL;
    float4* d1 = (float4*)sBH;
    float4* d2 = (float4*)sBL;
    for (int i = tid; i < 2048; i += 256) { d1[i] = s1p[i]; d2[i] = s2p[i]; }
  }
  __syncthreads();

  const float sgw3 = SC[0], cb = SC[1];

#pragma unroll 1
  for (int it = 0; it < 6; ++it) {           // uniform trip count
    const int wt = blockIdx.x * 24 + it * 4 + wave;   // < 12240 always
    const int g0 = wt * 32;
    const int b = g0 / EDGES;                // 32 | EDGES: no batch crossing
    const int e0 = g0 - b * EDGES;
    const int bofs = (b << 9);

    // ---- stage 1: raw h -> bf16 hi/lo A-frags at load; stats as partials ----
    s16x8 Ah[2][4], Al[2][4];
    float s1v[2], q1v[2];
#pragma unroll
    for (int mt = 0; mt < 2; ++mt) {
      const int2 ss = map[e0 + mt * 16 + cl];
      const float* pr = P + ((size_t)(bofs + ss.x) << 7) + qd * 8;
      const float* qr = Q + ((size_t)(bofs + ss.y) << 7) + qd * 8;
      float s1 = 0.f, q1 = 0.f;
#pragma unroll
      for (int kt = 0; kt < 4; ++kt) {
        const float4 pa = *(const float4*)(pr + kt * 32);
        const float4 pb = *(const float4*)(pr + kt * 32 + 4);
        const float4 qa = *(const float4*)(qr + kt * 32);
        const float4 qb = *(const float4*)(qr + kt * 32 + 4);
        const float uu[8] = {
            fmaxf(pa.x + qa.x, 0.f), fmaxf(pa.y + qa.y, 0.f),
            fmaxf(pa.z + qa.z, 0.f), fmaxf(pa.w + qa.w, 0.f),
            fmaxf(pb.x + qb.x, 0.f), fmaxf(pb.y + qb.y, 0.f),
            fmaxf(pb.z + qb.z, 0.f), fmaxf(pb.w + qb.w, 0.f)};
#pragma unroll
        for (int j = 0; j < 8; ++j) {
          const float h = uu[j];
          s1 += h;
          q1 = fmaf(h, h, q1);
          const uint32_t xu = __float_as_uint(h);
          const float d = h - __uint_as_float(xu & 0xFFFF0000u);
          Ah[mt][kt][j] = (short)(xu >> 16);
          Al[mt][kt][j] = (short)(__float_as_uint(d) >> 16);
        }
      }
      s1v[mt] = s1;
      q1v[mt] = q1;
      __builtin_amdgcn_sched_barrier(0);     // cap in-flight loads per mt
    }

    // ---- stage 2: 3-product bf16-split MFMA; 2-slot depth-2 B pipeline ----
    f32x4 acc[2][8];
#pragma unroll
    for (int mt = 0; mt < 2; ++mt)
#pragma unroll
      for (int nt = 0; nt < 8; ++nt) acc[mt][nt] = (f32x4){0.f, 0.f, 0.f, 0.f};

    s16x8 Bh[2][2], Bl[2][2];                // [slot][pair] — 32 VGPRs
#pragma unroll
    for (int s = 0; s < 2; ++s) {            // preload groups 0,1
      const int base = ((s >> 2) * 8 + (s & 3) * 2) * 64 + lane;
      Bh[s][0] = sBH[base];      Bl[s][0] = sBL[base];
      Bh[s][1] = sBH[base + 64]; Bl[s][1] = sBL[base + 64];
    }
#pragma unroll
    for (int g = 0; g < 16; ++g) {           // g = kt*4 + np
      const int kt = g >> 2;
      const int n0 = (g & 3) * 2, n1 = n0 + 1;
      const int sl = g & 1;
      acc[0][n0] = __builtin_amdgcn_mfma_f32_16x16x32_bf16(Ah[0][kt], Bh[sl][0], acc[0][n0], 0, 0, 0);
      acc[1][n0] = __builtin_amdgcn_mfma_f32_16x16x32_bf16(Ah[1][kt], Bh[sl][0], acc[1][n0], 0, 0, 0);
      acc[0][n1] = __builtin_amdgcn_mfma_f32_16x16x32_bf16(Ah[0][kt], Bh[sl][1], acc[0][n1], 0, 0, 0);
      acc[1][n1] = __builtin_amdgcn_mfma_f32_16x16x32_bf16(Ah[1][kt], Bh[sl][1], acc[1][n1], 0, 0, 0);
      acc[0][n0] = __builtin_amdgcn_mfma_f32_16x16x32_bf16(Al[0][kt], Bh[sl][0], acc[0][n0], 0, 0, 0);
      acc[1][n0] = __builtin_amdgcn_mfma_f32_16x16x32_bf16(Al[1][kt], Bh[sl][0], acc[1][n0], 0, 0, 0);
      acc[0][n1] = __builtin_amdgcn_mfma_f32_16x16x32_bf16(Al[0][kt], Bh[sl][1], acc[0][n1], 0, 0, 0);
      acc[1][n1] = __builtin_amdgcn_mfma_f32_16x16x32_bf16(Al[1][kt], Bh[sl][1], acc[1][n1], 0, 0, 0);
      acc[0][n0] = __builtin_amdgcn_mfma_f32_16x16x32_bf16(Ah[0][kt], Bl[sl][0], acc[0][n0], 0, 0, 0);
      acc[1][n0] = __builtin_amdgcn_mfma_f32_16x16x32_bf16(Ah[1][kt], Bl[sl][0], acc[1][n0], 0, 0, 0);
      acc[0][n1] = __builtin_amdgcn_mfma_f32_16x16x32_bf16(Ah[0][kt], Bl[sl][1], acc[0][n1], 0, 0, 0);
      acc[1][n1] = __builtin_amdgcn_mfma_f32_16x16x32_bf16(Ah[1][kt], Bl[sl][1], acc[1][n1], 0, 0, 0);
      if (g < 14) {                          // refill this slot for group g+2
        const int g2 = g + 2;
        const int base = ((g2 >> 2) * 8 + (g2 & 3) * 2) * 64 + lane;
        Bh[sl][0] = sBH[base];      Bl[sl][0] = sBL[base];
        Bh[sl][1] = sBH[base + 64]; Bl[sl][1] = sBL[base + 64];
      }
      __builtin_amdgcn_sched_barrier(0);     // bound live set per group
    }

    // ---- finalize LN1 stats (post-MFMA) ----
    float mu[2], rs[2];
#pragma unroll
    for (int mt = 0; mt < 2; ++mt) {
      float s1 = s1v[mt], q1 = q1v[mt];
      s1 += __shfl_xor(s1, 16, 64);
      s1 += __shfl_xor(s1, 32, 64);
      q1 += __shfl_xor(q1, 16, 64);
      q1 += __shfl_xor(q1, 32, 64);
      mu[mt] = s1 * (1.0f / 128.0f);
      const float var = fmaxf(q1 * (1.0f / 128.0f) - mu[mt] * mu[mt], 0.0f);
      rs[mt] = rsqrtf(var + 1e-5f);
    }

    // ---- epilogue: LN1 fold, relu, LN2+W3 fold; DPP row reductions ----
    int zz;
    asm volatile("v_mov_b32 %0, 0" : "=v"(zz));
    float SGn[8], SBn[8], GWn[8];
#pragma unroll
    for (int nt = 0; nt < 8; ++nt) {
      const int n = nt * 16 + cl + zz;
      SGn[nt] = SG[n];
      SBn[nt] = SB[n];
      GWn[nt] = GW3[n];
    }
#pragma unroll
    for (int mt = 0; mt < 2; ++mt) {
#pragma unroll
      for (int r = 0; r < 4; ++r) {
        const int me = qd * 4 + r;            // edge row within mt-tile
        const float mue = __shfl(mu[mt], me, 64);
        const float rse = __shfl(rs[mt], me, 64);
        float s2 = 0.f, q2 = 0.f, t = 0.f;
#pragma unroll
        for (int nt = 0; nt < 8; ++nt) {
          const float Sraw = acc[mt][nt][r];
          const float z = fmaf(rse, fmaf(-mue, SGn[nt], Sraw), SBn[nt]);
          const float h2 = fmaxf(z, 0.f);
          s2 += h2;
          q2 = fmaf(h2, h2, q2);
          t = fmaf(h2, GWn[nt], t);
        }
        s2 = row_sum16(s2);                   // DPP (VALU), not DS
        q2 = row_sum16(q2);
        t  = row_sum16(t);
        if (cl == 0) {
          const float mu2 = s2 * (1.0f / 128.0f);
          const float var2 = fmaxf(q2 * (1.0f / 128.0f) - mu2 * mu2, 0.0f);
          const float rs2 = rsqrtf(var2 + 1e-5f);
          logits[g0 + mt * 16 + me] = rs2 * (t - mu2 * sgw3) + cb;
        }
      }
    }
  }
}

// ---------------- gumbel argmax, stage 1: per-(bs,chunk) best ----------------
__global__ __launch_bounds__(256) void gumbel_kernel(
    const float* __restrict__ logits, float* __restrict__ bestval,
    int* __restrict__ bestidx) {
  const int bs = blockIdx.x / CHUNKS;     // b*5 + s
  const int chunk = blockIdx.x % CHUNKS;
  const int b = bs / NSAMP;
  const float* lg = logits + b * EDGES;
  float best = -1e30f; int bi = 0x7fffffff;
  for (int e = chunk * 256 + threadIdx.x; e < EDGES; e += CHUNKS * 256) {
    uint32_t n = (uint32_t)(bs * EDGES + e);
    float val = lg[e] + gumbel_valf(n);
    if (val > best) { best = val; bi = e; }
  }
  __shared__ float sv[256];
  __shared__ int si[256];
  sv[threadIdx.x] = best; si[threadIdx.x] = bi;
  __syncthreads();
  for (int off = 128; off; off >>= 1) {
    if (threadIdx.x < off) {
      float ov = sv[threadIdx.x + off]; int oi = si[threadIdx.x + off];
      if (ov > sv[threadIdx.x] ||
          (ov == sv[threadIdx.x] && oi < si[threadIdx.x])) {
        sv[threadIdx.x] = ov; si[threadIdx.x] = oi;
      }
    }
    __syncthreads();
  }
  if (threadIdx.x == 0) { bestval[blockIdx.x] = sv[0]; bestidx[blockIdx.x] = si[0]; }
}

// ---------------- gumbel argmax, stage 2: winner -> adj ----------------------
__global__ __launch_bounds__(64) void select_kernel(
    const float* __restrict__ bestval, const int* __restrict__ bestidx,
    const int2* __restrict__ map, float* __restrict__ adj) {
  const int bs = blockIdx.x;
  const int lane = threadIdx.x;
  float v = -1e30f; int idx = 0x7fffffff;
  if (lane < CHUNKS) { v = bestval[bs * CHUNKS + lane]; idx = bestidx[bs * CHUNKS + lane]; }
#pragma unroll
  for (int off = 32; off; off >>= 1) {
    float ov = __shfl_xor(v, off, 64);
    int oi = __shfl_xor(idx, off, 64);
    if (ov > v || (ov == v && oi < idx)) { v = ov; idx = oi; }
  }
  if (lane == 0) {
    int b = bs / NSAMP;
    int2 ss = map[idx];
    adj[((b * NNODES) + ss.x) * NNODES + ss.y] = 1.0f;
  }
}

extern "C" void kernel_launch(void* const* d_in, const int* in_sizes, int n_in,
                              void* d_out, int out_size, void* d_ws, size_t ws_size,
                              hipStream_t stream) {
  const float* nodes = (const float*)d_in[0];
  const float* W1  = (const float*)d_in[1];
  const float* b1  = (const float*)d_in[2];
  const float* g1  = (const float*)d_in[3];
  const float* be1 = (const float*)d_in[4];
  const float* W2  = (const float*)d_in[5];
  const float* b2  = (const float*)d_in[6];
  const float* g2  = (const float*)d_in[7];
  const float* be2 = (const float*)d_in[8];
  const float* W3  = (const float*)d_in[9];
  const float* b3  = (const float*)d_in[10];
  float* adj = (float*)d_out;

  char* ws = (char*)d_ws;
  float* P       = (float*)(ws);                       // 1 MB  [2048][128]
  float* Q       = (float*)(ws + (1 << 20));           // 1 MB
  int2*  map     = (int2*) (ws + (2 << 20));           // 783 KB
  float* logits  = (float*)(ws + (3 << 20));           // 1.57 MB
  unsigned short* GFH = (unsigned short*)(ws + (5 << 20));           // 32 KB
  unsigned short* GFL = (unsigned short*)(ws + (5 << 20) + 32768);   // 32 KB
  float* SG      = (float*)(ws + (5 << 20) + 65536);
  float* SB      = (float*)(ws + (5 << 20) + 66048);
  float* GW3     = (float*)(ws + (5 << 20) + 66560);
  float* SC      = (float*)(ws + (5 << 20) + 67072);
  float* bestval = (float*)(ws + (5 << 20) + 131072);  // 800*4
  int*   bestidx = (int*)  (ws + (5 << 20) + 137472);  // 800*4

  setup_kernel<<<SETUP_GRID, 256, 0, stream>>>(
      nodes, W1, b1, W2, g1, be1, b2, g2, be2, W3, b3,
      P, Q, map, GFH, GFL, SG, SB, GW3, SC, adj);
  mlp_kernel<<<MLP_GRID, 256, 0, stream>>>(P, Q, map, GFH, GFL,
                                           SG, SB, GW3, SC, logits);
  gumbel_kernel<<<20 * CHUNKS, 256, 0, stream>>>(logits, bestval, bestidx);
  select_kernel<<<20, 64, 0, stream>>>(bestval, bestidx, map, adj);
}